// Round 3
// baseline (56613.208 us; speedup 1.0000x reference)
//
#include <hip/hip_runtime.h>
#include <math.h>

#define NCHAR 256
#define NHID 2048
#define NSTACK 32
#define STACK 512
#define T 4096
#define NB 64           // persistent blocks (one flag per wave lane)
#define BT 1024         // 16 waves
#define RPB 32          // hid2hid rows per block (2 per wave)
#define AGENT __HIP_MEMORY_SCOPE_AGENT

__device__ __forceinline__ float cohLoadF(const float* p) {
  return __hip_atomic_load(p, __ATOMIC_RELAXED, AGENT);
}
__device__ __forceinline__ void cohStoreF(float* p, float v) {
  __hip_atomic_store(p, v, __ATOMIC_RELAXED, AGENT);
}

__global__ __launch_bounds__(BT) void stackrnn_seq(
    const int* __restrict__ tokens,
    const float* __restrict__ in2hid,    // [NHID][NCHAR]
    const float* __restrict__ hid2hid,   // [NHID][NHID]
    const float* __restrict__ hid2act,   // [NSTACK][3][NHID]
    const float* __restrict__ hid2stack, // [NSTACK][STACK][NHID]
    const float* __restrict__ stack2hid, // [NSTACK][NHID][STACK]
    const float* __restrict__ hid2out,   // [NCHAR][NHID]
    float* __restrict__ out,             // [T][NCHAR] logits (softmax later)
    float* __restrict__ Hbuf,            // [2][NHID]
    float* __restrict__ Pbuf,            // [2][NB][128] partial logits
    float* __restrict__ TopsG,           // [2][NSTACK][5]
    int*   __restrict__ flags)           // [NB]
{
  __shared__ int    sTok[T];             // 16 KB
  __shared__ float4 sH[576];             // h_{w-1}, padded i+(i>>3)
  __shared__ float  sLpart[4][128];
  __shared__ float  sL[128];
  __shared__ float  sTgL[160];
  __shared__ float  sActs[NSTACK][3];
  __shared__ float  sTopv[NSTACK];
  __shared__ float  sTops[NSTACK][4];
  __shared__ float  sSt[2][STACK];       // own stack neighbor exchange
  __shared__ float  sLl[16][128];        // per-wave logit partials
  __shared__ float  sOut[16];

  const int tid = threadIdx.x;
  const int b   = blockIdx.x;
  const int wv  = tid >> 6;
  const int l   = tid & 63;
  const int r0  = b * RPB + 2 * wv;
  const int r1  = r0 + 1;

  // ---- register-resident hid2hid rows (2 rows x 32 cols per lane) ----
  float wA[32], wB[32];
  {
    const float4* pa = (const float4*)(hid2hid + (size_t)r0 * NHID + 32 * l);
    const float4* pb = (const float4*)(hid2hid + (size_t)r1 * NHID + 32 * l);
#pragma unroll
    for (int j = 0; j < 8; ++j) {
      float4 v = pa[j];
      wA[4*j] = v.x; wA[4*j+1] = v.y; wA[4*j+2] = v.z; wA[4*j+3] = v.w;
    }
#pragma unroll
    for (int j = 0; j < 8; ++j) {
      float4 v = pb[j];
      wB[4*j] = v.x; wB[4*j+1] = v.y; wB[4*j+2] = v.z; wB[4*j+3] = v.w;
    }
  }
  // ---- logit-partial weights: lane handles logits 2l,2l+1 at rows r0,r1 ----
  float wl00, wl01, wl10, wl11;
  {
    const int lg0 = 2 * l, lg1 = 2 * l + 1;
    const float* p0 = (lg0 < 96) ? (hid2act + (size_t)lg0 * NHID)
                                 : (hid2stack + (size_t)(lg0 - 96) * STACK * NHID);
    const float* p1 = (lg1 < 96) ? (hid2act + (size_t)lg1 * NHID)
                                 : (hid2stack + (size_t)(lg1 - 96) * STACK * NHID);
    wl00 = p0[r0]; wl01 = p0[r1];
    wl10 = p1[r0]; wl11 = p1[r1];
  }
  // ---- stack2hid slice: lane covers stack cs, depths cd,cd+1 ----
  const int cs = l >> 1, cd = (l & 1) * 2;
  float w2a0, w2a1, w2b0, w2b1;
  {
    const float* p = stack2hid + (size_t)cs * NHID * STACK;
    w2a0 = p[(size_t)r0 * STACK + cd]; w2a1 = p[(size_t)r0 * STACK + cd + 1];
    w2b0 = p[(size_t)r1 * STACK + cd]; w2b1 = p[(size_t)r1 * STACK + cd + 1];
  }
  // ---- output-column weights: wave wv -> col 4b+(wv&3), seg (wv>>2)*512 ----
  const int ocol = 4 * b + (wv & 3);
  const int oseg = wv >> 2;
  float wo[8];
  {
    const float4* p = (const float4*)(hid2out + (size_t)ocol * NHID + oseg * 512 + 8 * l);
    float4 v0 = p[0], v1 = p[1];
    wo[0] = v0.x; wo[1] = v0.y; wo[2] = v0.z; wo[3] = v0.w;
    wo[4] = v1.x; wo[5] = v1.y; wo[6] = v1.z; wo[7] = v1.w;
  }

  for (int i = tid; i < T; i += BT) sTok[i] = tokens[i];

  // ---- stack ownership: even blocks own stack b/2, one element per thread ----
  const int sOwn = b >> 1;
  float bval = -1.f;

  __syncthreads();

#pragma unroll 1
  for (int w = 0; w < T; ++w) {
    const int pw_ = w & 1, pr_ = pw_ ^ 1;
    const int xt  = sTok[w];

    // ---- single sync point per step ----
    if (w > 0 && wv == 0) {
      int v;
      do {
        v = __hip_atomic_load(&flags[l], __ATOMIC_RELAXED, AGENT);
      } while (__any(v < w));
    }
    __syncthreads();

    // ---- one parallel coherent-load round: h, P, tops ----
    if (w > 0) {
      if (tid >= 512) {
        const int u = tid - 512;
        const float* hb = Hbuf + (size_t)pr_ * NHID + 4 * u;
        float a0 = cohLoadF(hb), a1 = cohLoadF(hb + 1);
        float a2 = cohLoadF(hb + 2), a3 = cohLoadF(hb + 3);
        sH[u + (u >> 3)] = make_float4(a0, a1, a2, a3);
      } else {
        const int k = tid >> 7, j = tid & 127;
        const float* pp = Pbuf + (size_t)pr_ * NB * 128 + (size_t)(16 * k) * 128 + j;
        float s = 0.f;
#pragma unroll
        for (int q = 0; q < 16; ++q) s += cohLoadF(pp + q * 128);
        sLpart[k][j] = s;
        if (tid < 160) sTgL[tid] = cohLoadF(&TopsG[(size_t)pr_ * 160 + tid]);
      }
    }
    const float e0 = in2hid[(size_t)r0 * NCHAR + xt];
    const float e1 = in2hid[(size_t)r1 * NCHAR + xt];
    __syncthreads();

    // ---- finalize logits; matvec h-part (overlapped) ----
    if (w > 0 && tid < 128)
      sL[tid] = sLpart[0][tid] + sLpart[1][tid] + sLpart[2][tid] + sLpart[3][tid];
    float acc0 = 0.f, acc1 = 0.f;
    if (w > 0) {
#pragma unroll
      for (int j = 0; j < 8; ++j) {
        const float4 hv = sH[9 * l + j];
        acc0 += wA[4*j]*hv.x + wA[4*j+1]*hv.y + wA[4*j+2]*hv.z + wA[4*j+3]*hv.w;
        acc1 += wB[4*j]*hv.x + wB[4*j+1]*hv.y + wB[4*j+2]*hv.z + wB[4*j+3]*hv.w;
      }
    }
    __syncthreads();

    // ---- acts/topv/tops of stacks_{w-1} (threads 0..31) ----
    if (tid < NSTACK) {
      if (w > 0) {
        const float la0 = sL[3 * tid], la1 = sL[3 * tid + 1], la2 = sL[3 * tid + 2];
        const float m  = fmaxf(la0, fmaxf(la1, la2));
        const float ea = expf(la0 - m), eb = expf(la1 - m), ec = expf(la2 - m);
        const float inv = 1.f / (ea + eb + ec);
        const float qw = ea * inv, pwt = eb * inv, nw = ec * inv;
        sActs[tid][0] = qw; sActs[tid][1] = pwt; sActs[tid][2] = nw;
        float tv = fminf(50.f, fmaxf(-50.f, sL[96 + tid]));
        tv = 1.f / (1.f + expf(-tv));
        sTopv[tid] = tv;
        const float tg0 = sTgL[tid * 5],     tg1 = sTgL[tid * 5 + 1];
        const float tg2 = sTgL[tid * 5 + 2], tg3 = sTgL[tid * 5 + 3];
        const float tg4 = sTgL[tid * 5 + 4];
        sTops[tid][0] = pwt * tv  + qw * tg1 + nw * tg0;
        sTops[tid][1] = pwt * tg0 + qw * tg2 + nw * tg1;
        sTops[tid][2] = pwt * tg1 + qw * tg3 + nw * tg2;
        sTops[tid][3] = pwt * tg2 + qw * tg4 + nw * tg3;
      } else {
        sActs[tid][0] = sActs[tid][1] = sActs[tid][2] = 0.f;
        sTopv[tid] = 0.f;
        sTops[tid][0] = sTops[tid][1] = sTops[tid][2] = sTops[tid][3] = -1.f;
      }
    }
    __syncthreads();

    // ---- finish matvec, h rows, logit partials ----
    acc0 += w2a0 * sTops[cs][cd] + w2a1 * sTops[cs][cd + 1];
    acc1 += w2b0 * sTops[cs][cd] + w2b1 * sTops[cs][cd + 1];
#pragma unroll
    for (int m = 1; m < 64; m <<= 1) {
      acc0 += __shfl_xor(acc0, m);
      acc1 += __shfl_xor(acc1, m);
    }
    const float h0 = 1.f / (1.f + expf(-(acc0 + e0)));
    const float h1 = 1.f / (1.f + expf(-(acc1 + e1)));
    if (l == 0) {
      cohStoreF(&Hbuf[(size_t)pw_ * NHID + r0], h0);
      cohStoreF(&Hbuf[(size_t)pw_ * NHID + r1], h1);
    }
    sLl[wv][2 * l]     = wl00 * h0 + wl01 * h1;
    sLl[wv][2 * l + 1] = wl10 * h0 + wl11 * h1;

    // ---- own-stack blend (even blocks, threads 512..1023: depth d) ----
    if ((b & 1) == 0 && tid >= 512) {
      const int d = tid - 512;
      float nv;
      if (w > 0) {
        const float left   = (d > 0) ? sSt[pr_][d - 1] : 0.f;
        const float pushed = (d == 0) ? sTopv[sOwn] : left;
        const float popped = (d < STACK - 1) ? sSt[pr_][d + 1] : -1.f;
        nv = sActs[sOwn][1] * pushed + sActs[sOwn][0] * popped + sActs[sOwn][2] * bval;
      } else {
        nv = -1.f;
      }
      bval = nv;
      sSt[pw_][d] = nv;
      if (d < 5) cohStoreF(&TopsG[(size_t)pw_ * 160 + sOwn * 5 + d], nv);
    }

    // ---- deferred output columns of h_{w-1} ----
    if (w > 0) {
      const int f0 = oseg * 128 + 2 * l;
      const float4 hv0 = sH[f0 + (f0 >> 3)];
      const float4 hv1 = sH[(f0 + 1) + ((f0 + 1) >> 3)];
      float dv = wo[0]*hv0.x + wo[1]*hv0.y + wo[2]*hv0.z + wo[3]*hv0.w
               + wo[4]*hv1.x + wo[5]*hv1.y + wo[6]*hv1.z + wo[7]*hv1.w;
#pragma unroll
      for (int m = 1; m < 64; m <<= 1) dv += __shfl_xor(dv, m);
      if (l == 0) sOut[wv] = dv;
    }
    __syncthreads();

    // ---- P row store + out finalize ----
    if (tid < 128) {
      float pv = 0.f;
#pragma unroll
      for (int g = 0; g < 16; ++g) pv += sLl[g][tid];
      cohStoreF(&Pbuf[(size_t)pw_ * NB * 128 + (size_t)b * 128 + tid], pv);
    }
    if (w > 0 && tid < 4)
      out[(size_t)(w - 1) * NCHAR + 4 * b + tid] =
          sOut[tid] + sOut[4 + tid] + sOut[8 + tid] + sOut[12 + tid];

    asm volatile("s_waitcnt vmcnt(0)" ::: "memory");  // per-wave store drain
    __syncthreads();                                  // all waves drained
    if (tid == 0)
      __hip_atomic_store(&flags[b], w + 1, __ATOMIC_RELAXED, AGENT);
  }

  // ---- tail: output columns of h_{T-1} ----
  if (wv == 0) {
    int v;
    do {
      v = __hip_atomic_load(&flags[l], __ATOMIC_RELAXED, AGENT);
    } while (__any(v < T));
  }
  __syncthreads();
  {
    const float* hb = Hbuf + (size_t)((T - 1) & 1) * NHID + oseg * 512 + 8 * l;
    float dv = 0.f;
#pragma unroll
    for (int e = 0; e < 8; ++e) dv += wo[e] * cohLoadF(hb + e);
#pragma unroll
    for (int m = 1; m < 64; m <<= 1) dv += __shfl_xor(dv, m);
    if (l == 0) sOut[wv] = dv;
  }
  __syncthreads();
  if (tid < 4)
    out[(size_t)(T - 1) * NCHAR + 4 * b + tid] =
        sOut[tid] + sOut[4 + tid] + sOut[8 + tid] + sOut[12 + tid];
}

// ---------------- row softmax over NCHAR=256 ----------------
__global__ __launch_bounds__(64) void row_softmax(float* __restrict__ out) {
  const int t = blockIdx.x;
  const int l = threadIdx.x;
  float4* p = (float4*)(out + (size_t)t * NCHAR);
  float4 v = p[l];
  float m = fmaxf(fmaxf(v.x, v.y), fmaxf(v.z, v.w));
#pragma unroll
  for (int k = 1; k < 64; k <<= 1) m = fmaxf(m, __shfl_xor(m, k));
  const float ex = expf(v.x - m), ey = expf(v.y - m);
  const float ez = expf(v.z - m), ew = expf(v.w - m);
  float s = ex + ey + ez + ew;
#pragma unroll
  for (int k = 1; k < 64; k <<= 1) s += __shfl_xor(s, k);
  const float inv = 1.f / s;
  p[l] = make_float4(ex * inv, ey * inv, ez * inv, ew * inv);
}

extern "C" void kernel_launch(void* const* d_in, const int* in_sizes, int n_in,
                              void* d_out, int out_size, void* d_ws, size_t ws_size,
                              hipStream_t stream) {
  const int*   tokens    = (const int*)d_in[0];
  const float* in2hid    = (const float*)d_in[1];
  const float* hid2hid   = (const float*)d_in[2];
  const float* hid2act   = (const float*)d_in[3];
  const float* hid2stack = (const float*)d_in[4];
  const float* stack2hid = (const float*)d_in[5];
  const float* hid2out   = (const float*)d_in[6];
  float* out = (float*)d_out;

  float* ws    = (float*)d_ws;
  float* Hbuf  = ws;                          // 2*NHID = 4096
  float* Pbuf  = Hbuf + 2 * NHID;             // 2*NB*128 = 16384
  float* TopsG = Pbuf + 2 * NB * 128;         // 2*160 = 320
  int*   flags = (int*)(TopsG + 320);         // NB

  hipLaunchKernelGGL(stackrnn_seq, dim3(NB), dim3(BT), 0, stream,
                     tokens, in2hid, hid2hid, hid2act, hid2stack, stack2hid,
                     hid2out, out, Hbuf, Pbuf, TopsG, flags);
  hipLaunchKernelGGL(row_softmax, dim3(T), dim3(64), 0, stream, out);
}

// Round 4
// 33493.152 us; speedup vs baseline: 1.6903x; 1.6903x over previous
//
#include <hip/hip_runtime.h>
#include <math.h>

#define NCHAR 256
#define NHID 2048
#define NSTACK 32
#define STACK 512
#define T 4096
#define NB 64           // persistent blocks (one flag per wave lane)
#define BT 1024         // 16 waves
#define RPB 32          // hid2hid rows per block (2 per wave)
#define PROW 128        // partial-logit row length
#define FPAD 16         // flag padding in ints (64B line per block)
#define AGENT __HIP_MEMORY_SCOPE_AGENT

__device__ __forceinline__ float cohLoadF(const float* p) {
  return __hip_atomic_load(p, __ATOMIC_RELAXED, AGENT);
}
__device__ __forceinline__ void cohStoreF(float* p, float v) {
  __hip_atomic_store(p, v, __ATOMIC_RELAXED, AGENT);
}
// one coherent 16B load (own waitcnt)
__device__ __forceinline__ float4 cohLoad4(const float4* p) {
  float4 r;
  asm volatile("global_load_dwordx4 %0, %1, off sc0 sc1\n\ts_waitcnt vmcnt(0)"
               : "=&v"(r) : "v"(p) : "memory");
  return r;
}
// four coherent 16B loads in flight, single waitcnt
__device__ __forceinline__ void cohLoad4x4(const float4* p0, const float4* p1,
                                           const float4* p2, const float4* p3,
                                           float4& r0, float4& r1,
                                           float4& r2, float4& r3) {
  asm volatile(
      "global_load_dwordx4 %0, %4, off sc0 sc1\n\t"
      "global_load_dwordx4 %1, %5, off sc0 sc1\n\t"
      "global_load_dwordx4 %2, %6, off sc0 sc1\n\t"
      "global_load_dwordx4 %3, %7, off sc0 sc1\n\t"
      "s_waitcnt vmcnt(0)"
      : "=&v"(r0), "=&v"(r1), "=&v"(r2), "=&v"(r3)
      : "v"(p0), "v"(p1), "v"(p2), "v"(p3)
      : "memory");
}

__global__ __launch_bounds__(BT, 4) void stackrnn_seq(
    const int* __restrict__ tokens,
    const float* __restrict__ in2hid,    // [NHID][NCHAR]
    const float* __restrict__ hid2hid,   // [NHID][NHID]
    const float* __restrict__ hid2act,   // [NSTACK][3][NHID]
    const float* __restrict__ hid2stack, // [NSTACK][STACK][NHID]
    const float* __restrict__ stack2hid, // [NSTACK][NHID][STACK]
    const float* __restrict__ hid2out,   // [NCHAR][NHID]
    float* __restrict__ out,             // [T][NCHAR] logits (softmax later)
    float* __restrict__ Hbuf,            // [2][NHID]
    float* __restrict__ Pbuf,            // [2][NB][PROW] partial logits (quad-permuted)
    float* __restrict__ TopsG,           // [2][NSTACK][16] raw stack tops (padded)
    int*   __restrict__ flags)           // [NB*FPAD]
{
  __shared__ int    sTok[T];             // 16 KB
  __shared__ float4 sH[576];             // h_{w-1}, padded i+(i>>3)
  __shared__ float4 sPq[32][17];         // stage-1 P partials (padded)
  __shared__ float  sLl[16][128];        // per-wave logit partials
  __shared__ float  sSt[2][STACK];       // owner stack neighbor exchange
  __shared__ float  sHnew[RPB];          // this block's new h rows
  __shared__ float  sActs[NSTACK][3];
  __shared__ float  sTopv[NSTACK];
  __shared__ float  sTops[NSTACK][4];
  __shared__ float  sOut[16];

  const int tid = threadIdx.x;
  const int b   = blockIdx.x;
  const int wv  = tid >> 6;
  const int l   = tid & 63;
  const int r0  = b * RPB + 2 * wv;
  const int r1  = r0 + 1;

  // ---- register-resident hid2hid rows (2 rows x 32 cols per lane) ----
  float wA[32], wB[32];
  {
    const float4* pa = (const float4*)(hid2hid + (size_t)r0 * NHID + 32 * l);
    const float4* pb = (const float4*)(hid2hid + (size_t)r1 * NHID + 32 * l);
#pragma unroll
    for (int j = 0; j < 8; ++j) {
      float4 v = pa[j];
      wA[4*j] = v.x; wA[4*j+1] = v.y; wA[4*j+2] = v.z; wA[4*j+3] = v.w;
    }
#pragma unroll
    for (int j = 0; j < 8; ++j) {
      float4 v = pb[j];
      wB[4*j] = v.x; wB[4*j+1] = v.y; wB[4*j+2] = v.z; wB[4*j+3] = v.w;
    }
  }
  // ---- P weights, quad-permuted: logit g=4s+k -> (k<3 ? act : topv) ----
  float wl00, wl01, wl10, wl11;
  {
    const int g0 = 2 * l, g1 = 2 * l + 1;
    const int s0 = g0 >> 2, k0 = g0 & 3, s1 = g1 >> 2, k1 = g1 & 3;
    const float* p0 = (k0 < 3) ? (hid2act + (size_t)(3 * s0 + k0) * NHID)
                               : (hid2stack + (size_t)s0 * STACK * NHID);
    const float* p1 = (k1 < 3) ? (hid2act + (size_t)(3 * s1 + k1) * NHID)
                               : (hid2stack + (size_t)s1 * STACK * NHID);
    wl00 = p0[r0]; wl01 = p0[r1];
    wl10 = p1[r0]; wl11 = p1[r1];
  }
  // ---- stack2hid slice: lane covers stack cs, depths cd,cd+1 ----
  const int cs = l >> 1, cd = (l & 1) * 2;
  float w2a0, w2a1, w2b0, w2b1;
  {
    const float* p = stack2hid + (size_t)cs * NHID * STACK;
    w2a0 = p[(size_t)r0 * STACK + cd]; w2a1 = p[(size_t)r0 * STACK + cd + 1];
    w2b0 = p[(size_t)r1 * STACK + cd]; w2b1 = p[(size_t)r1 * STACK + cd + 1];
  }
  // ---- output-column weights: wave wv -> col 4b+(wv&3), seg (wv>>2) ----
  const int oseg = wv >> 2;
  float wo[8];
  {
    const int ocol = 4 * b + (wv & 3);
    const float4* p = (const float4*)(hid2out + (size_t)ocol * NHID + oseg * 512 + 8 * l);
    float4 v0 = p[0], v1 = p[1];
    wo[0] = v0.x; wo[1] = v0.y; wo[2] = v0.z; wo[3] = v0.w;
    wo[4] = v1.x; wo[5] = v1.y; wo[6] = v1.z; wo[7] = v1.w;
  }

  for (int i = tid; i < T; i += BT) sTok[i] = tokens[i];
  float bval = -1.f;   // owner blocks: stacks_{-1}[depth tid-512] = -1

  __syncthreads();

#pragma unroll 1
  for (int w = 0; w < T; ++w) {
    const int pw_ = w & 1, pr_ = pw_ ^ 1;
    const int xt  = sTok[w];
    const float e0 = in2hid[(size_t)r0 * NCHAR + xt];  // issued before poll
    const float e1 = in2hid[(size_t)r1 * NCHAR + xt];

    // ---- single sync point per step (padded flags, 1 load/lane) ----
    if (w > 0 && wv == 0) {
      int v;
      do {
        v = __hip_atomic_load(&flags[l * FPAD], __ATOMIC_RELAXED, AGENT);
      } while (__any(v < w));
    }
    __syncthreads();  // B1

    // ---- one parallel coherent-load round ----
    float tg0 = -1.f, tg1 = -1.f, tg2 = -1.f, tg3 = -1.f, tg4 = -1.f;
    if (w > 0) {
      if (tid >= 512) {
        const int u = tid - 512;
        float4 hv = cohLoad4((const float4*)(Hbuf + (size_t)pr_ * NHID) + u);
        sH[u + (u >> 3)] = hv;
      } else {
        const int q = tid >> 4, bg = tid & 15;
        const float* base = Pbuf + (size_t)pr_ * NB * PROW + (size_t)(4 * bg) * PROW + 4 * q;
        float4 a0, a1, a2, a3;
        cohLoad4x4((const float4*)base, (const float4*)(base + PROW),
                   (const float4*)(base + 2 * PROW), (const float4*)(base + 3 * PROW),
                   a0, a1, a2, a3);
        float4 s4;
        s4.x = a0.x + a1.x + a2.x + a3.x;
        s4.y = a0.y + a1.y + a2.y + a3.y;
        s4.z = a0.z + a1.z + a2.z + a3.z;
        s4.w = a0.w + a1.w + a2.w + a3.w;
        sPq[q][bg] = s4;
        if (tid < NSTACK) {
          const float* tp = TopsG + ((size_t)pr_ * NSTACK + tid) * 16;
          tg0 = cohLoadF(tp);     tg1 = cohLoadF(tp + 1); tg2 = cohLoadF(tp + 2);
          tg3 = cohLoadF(tp + 3); tg4 = cohLoadF(tp + 4);
        }
      }
    }
    __syncthreads();  // B2

    // ---- stage-2 logit reduce + acts/topv/blended tops (tid<32) ----
    if (tid < NSTACK) {
      if (w > 0) {
        float4 a = make_float4(0.f, 0.f, 0.f, 0.f);
#pragma unroll
        for (int g = 0; g < 16; ++g) {
          const float4 p = sPq[tid][(g + tid) & 15];
          a.x += p.x; a.y += p.y; a.z += p.z; a.w += p.w;
        }
        const float m  = fmaxf(a.x, fmaxf(a.y, a.z));
        const float ea = expf(a.x - m), eb = expf(a.y - m), ec = expf(a.z - m);
        const float inv = 1.f / (ea + eb + ec);
        const float qw = ea * inv, pwt = eb * inv, nw = ec * inv;  // pop,push,noop
        sActs[tid][0] = qw; sActs[tid][1] = pwt; sActs[tid][2] = nw;
        float tv = fminf(50.f, fmaxf(-50.f, a.w));
        tv = 1.f / (1.f + expf(-tv));
        sTopv[tid] = tv;
        sTops[tid][0] = pwt * tv  + qw * tg1 + nw * tg0;
        sTops[tid][1] = pwt * tg0 + qw * tg2 + nw * tg1;
        sTops[tid][2] = pwt * tg1 + qw * tg3 + nw * tg2;
        sTops[tid][3] = pwt * tg2 + qw * tg4 + nw * tg3;
      } else {
        sActs[tid][0] = sActs[tid][1] = sActs[tid][2] = 0.f;
        sTopv[tid] = 0.f;
        sTops[tid][0] = sTops[tid][1] = sTops[tid][2] = sTops[tid][3] = -1.f;
      }
    }
    // ---- matvec W·h_{w-1} (all threads, overlapped with stage-2) ----
    float acc0 = 0.f, acc1 = 0.f;
    if (w > 0) {
#pragma unroll
      for (int j = 0; j < 8; ++j) {
        const float4 hv = sH[9 * l + j];
        acc0 += wA[4*j]*hv.x + wA[4*j+1]*hv.y + wA[4*j+2]*hv.z + wA[4*j+3]*hv.w;
        acc1 += wB[4*j]*hv.x + wB[4*j+1]*hv.y + wB[4*j+2]*hv.z + wB[4*j+3]*hv.w;
      }
    }
    __syncthreads();  // B3: sTops/sActs/sTopv ready

    acc0 += w2a0 * sTops[cs][cd] + w2a1 * sTops[cs][cd + 1];
    acc1 += w2b0 * sTops[cs][cd] + w2b1 * sTops[cs][cd + 1];
#pragma unroll
    for (int m = 1; m < 64; m <<= 1) {
      acc0 += __shfl_xor(acc0, m);
      acc1 += __shfl_xor(acc1, m);
    }
    const float h0 = 1.f / (1.f + expf(-(acc0 + e0)));
    const float h1 = 1.f / (1.f + expf(-(acc1 + e1)));
    if (l == 0) { sHnew[2 * wv] = h0; sHnew[2 * wv + 1] = h1; }
    *(float2*)&sLl[wv][2 * l] =
        make_float2(wl00 * h0 + wl01 * h1, wl10 * h0 + wl11 * h1);

    // ---- owner stack blend (blocks 0..31, threads 512..1023: depth d) ----
    if (b < NSTACK && tid >= 512) {
      const int d = tid - 512;
      float nv;
      if (w > 0) {
        const float left   = (d > 0) ? sSt[pr_][d - 1] : 0.f;
        const float pushed = (d == 0) ? sTopv[b] : left;
        const float popped = (d < STACK - 1) ? sSt[pr_][d + 1] : -1.f;
        nv = sActs[b][1] * pushed + sActs[b][0] * popped + sActs[b][2] * bval;
      } else {
        nv = -1.f;
      }
      bval = nv;
      sSt[pw_][d] = nv;
      if (d < 5) cohStoreF(&TopsG[((size_t)pw_ * NSTACK + b) * 16 + d], nv);
    }
    // ---- deferred output columns of h_{w-1} ----
    if (w > 0) {
      const int f0 = oseg * 128 + 2 * l;
      const float4 hv0 = sH[f0 + (f0 >> 3)];
      const float4 hv1 = sH[(f0 + 1) + ((f0 + 1) >> 3)];
      float dv = wo[0]*hv0.x + wo[1]*hv0.y + wo[2]*hv0.z + wo[3]*hv0.w
               + wo[4]*hv1.x + wo[5]*hv1.y + wo[6]*hv1.z + wo[7]*hv1.w;
#pragma unroll
      for (int m = 1; m < 64; m <<= 1) dv += __shfl_xor(dv, m);
      if (l == 0) sOut[wv] = dv;
    }
    __syncthreads();  // B4

    // ---- write-combined publish ----
    if (tid < 128) {
      float pv = 0.f;
#pragma unroll
      for (int g = 0; g < 16; ++g) pv += sLl[g][tid];
      cohStoreF(&Pbuf[(size_t)pw_ * NB * PROW + (size_t)b * PROW + tid], pv);
    } else if (tid < 160) {
      cohStoreF(&Hbuf[(size_t)pw_ * NHID + b * RPB + (tid - 128)], sHnew[tid - 128]);
    }
    if (w > 0 && tid < 4)
      out[(size_t)(w - 1) * NCHAR + 4 * b + tid] =
          sOut[tid] + sOut[4 + tid] + sOut[8 + tid] + sOut[12 + tid];

    asm volatile("s_waitcnt vmcnt(0)" ::: "memory");  // per-wave store drain
    __syncthreads();                                  // B5: all waves drained
    if (tid == 0)
      __hip_atomic_store(&flags[b * FPAD], w + 1, __ATOMIC_RELAXED, AGENT);
  }

  // ---- tail: output columns of h_{T-1} ----
  if (wv == 0) {
    int v;
    do {
      v = __hip_atomic_load(&flags[l * FPAD], __ATOMIC_RELAXED, AGENT);
    } while (__any(v < T));
  }
  __syncthreads();
  {
    const float* hb = Hbuf + (size_t)((T - 1) & 1) * NHID + oseg * 512 + 8 * l;
    float dv = 0.f;
#pragma unroll
    for (int e = 0; e < 8; ++e) dv += wo[e] * cohLoadF(hb + e);
#pragma unroll
    for (int m = 1; m < 64; m <<= 1) dv += __shfl_xor(dv, m);
    if (l == 0) sOut[wv] = dv;
  }
  __syncthreads();
  if (tid < 4)
    out[(size_t)(T - 1) * NCHAR + 4 * b + tid] =
        sOut[tid] + sOut[4 + tid] + sOut[8 + tid] + sOut[12 + tid];
}

// ---------------- row softmax over NCHAR=256 ----------------
__global__ __launch_bounds__(64) void row_softmax(float* __restrict__ out) {
  const int t = blockIdx.x;
  const int l = threadIdx.x;
  float4* p = (float4*)(out + (size_t)t * NCHAR);
  float4 v = p[l];
  float m = fmaxf(fmaxf(v.x, v.y), fmaxf(v.z, v.w));
#pragma unroll
  for (int k = 1; k < 64; k <<= 1) m = fmaxf(m, __shfl_xor(m, k));
  const float ex = expf(v.x - m), ey = expf(v.y - m);
  const float ez = expf(v.z - m), ew = expf(v.w - m);
  float s = ex + ey + ez + ew;
#pragma unroll
  for (int k = 1; k < 64; k <<= 1) s += __shfl_xor(s, k);
  const float inv = 1.f / s;
  p[l] = make_float4(ex * inv, ey * inv, ez * inv, ew * inv);
}

extern "C" void kernel_launch(void* const* d_in, const int* in_sizes, int n_in,
                              void* d_out, int out_size, void* d_ws, size_t ws_size,
                              hipStream_t stream) {
  const int*   tokens    = (const int*)d_in[0];
  const float* in2hid    = (const float*)d_in[1];
  const float* hid2hid   = (const float*)d_in[2];
  const float* hid2act   = (const float*)d_in[3];
  const float* hid2stack = (const float*)d_in[4];
  const float* stack2hid = (const float*)d_in[5];
  const float* hid2out   = (const float*)d_in[6];
  float* out = (float*)d_out;

  float* ws    = (float*)d_ws;
  float* Hbuf  = ws;                          // 2*NHID = 4096 floats
  float* Pbuf  = Hbuf + 2 * NHID;             // 2*NB*PROW = 16384
  float* TopsG = Pbuf + 2 * NB * PROW;        // 2*32*16 = 1024
  int*   flags = (int*)(TopsG + 1024);        // NB*FPAD ints

  hipLaunchKernelGGL(stackrnn_seq, dim3(NB), dim3(BT), 0, stream,
                     tokens, in2hid, hid2hid, hid2act, hid2stack, stack2hid,
                     hid2out, out, Hbuf, Pbuf, TopsG, flags);
  hipLaunchKernelGGL(row_softmax, dim3(T), dim3(64), 0, stream, out);
}